// Round 2
// baseline (1303.974 us; speedup 1.0000x reference)
//
#include <hip/hip_runtime.h>
#include <math.h>

#define B_ 2
#define S_ 2048
#define H_ 12
#define DM_ 768
#define DH_ 64

// ===========================================================================
// LDS layout notes (all kernels):
//  - "A-operand" tiles (read as rows with a K-column index varying per step:
//    Xs, Qs, Ks, Ps, Zs) are stored [64][64] with an XOR swizzle on the
//    float4 column slot:  slot = c4 ^ ((row>>2)&7).
//    Reads &T[r][ (k4 ^ ((r>>2)&7)) * 4 ] then hit all 8 bank-quads across
//    the 16 distinct per-wave addresses (2-way aliasing = free, m136).
//    Padded row-major can NEVER achieve this for float4-aligned strides
//    (step 4*stride mod 32 is always 0 or 16 -> >=8-way conflict).
//  - "B-operand" tiles (read row-contiguous: Ws, Vs) are plain [64][64];
//    a row's 64 consecutive floats cover all 32 banks twice (free).
// ===========================================================================

// ---------------------------------------------------------------------------
// Kernel 1: fused QKV projection.
// grid (S/64, B*H, 3): 64(row)x64(=DH) tile of q/k/v for one (b,h).
// LDS-tiled SGEMM, BK=64, 4x4 acc per thread.
// Output layout: [B][H][S][DH].
// ---------------------------------------------------------------------------
__global__ __launch_bounds__(256) void qkv_proj_kernel(
    const float* __restrict__ Xq, const float* __restrict__ Xk, const float* __restrict__ Xv,
    const float* __restrict__ WQ, const float* __restrict__ bQ,
    const float* __restrict__ WK, const float* __restrict__ bK,
    const float* __restrict__ WV, const float* __restrict__ bV,
    float* __restrict__ qo, float* __restrict__ ko, float* __restrict__ vo)
{
    const int which = blockIdx.z;
    const float* __restrict__ X    = which==0 ? Xq : (which==1 ? Xk : Xv);
    const float* __restrict__ W    = which==0 ? WQ : (which==1 ? WK : WV);
    const float* __restrict__ bias = which==0 ? bQ : (which==1 ? bK : bV);
    float* __restrict__ out        = which==0 ? qo : (which==1 ? ko : vo);

    const int bh = blockIdx.y;
    const int b  = bh / H_, h = bh % H_;
    const int s0 = blockIdx.x * 64;

    __shared__ float Xs[64][64];   // swizzled A-tile
    __shared__ float Ws[64][64];   // plain B-tile

    const int t  = threadIdx.x;
    const int tx = t & 15, ty = t >> 4;
    const int keyY = ty & 7;

    float acc[4][4] = {};

    for (int k0 = 0; k0 < DM_; k0 += 64) {
        __syncthreads();
        #pragma unroll
        for (int l = 0; l < 4; ++l) {
            const int lin = t + l*256;
            const int row = lin >> 4, c4 = lin & 15;
            const float4 fx = *(const float4*)(X + ((size_t)((b*S_ + s0 + row)*H_ + h))*DM_ + k0 + c4*4);
            *(float4*)&Xs[row][(c4 ^ ((row>>2)&7)) << 2] = fx;
            const float4 fw = *(const float4*)(W + ((size_t)(h*DM_ + k0 + row))*DH_ + c4*4);
            *(float4*)&Ws[row][c4*4] = fw;
        }
        __syncthreads();
        #pragma unroll
        for (int k4 = 0; k4 < 16; ++k4) {
            float a[4][4], w[4][4];
            #pragma unroll
            for (int i = 0; i < 4; ++i)
                *(float4*)a[i] = *(const float4*)&Xs[ty*4+i][(k4 ^ keyY) << 2];
            #pragma unroll
            for (int qq = 0; qq < 4; ++qq)
                *(float4*)w[qq] = *(const float4*)&Ws[k4*4+qq][tx*4];
            #pragma unroll
            for (int i = 0; i < 4; ++i)
                #pragma unroll
                for (int j = 0; j < 4; ++j)
                    acc[i][j] = fmaf(a[i][0], w[0][j],
                                fmaf(a[i][1], w[1][j],
                                fmaf(a[i][2], w[2][j],
                                fmaf(a[i][3], w[3][j], acc[i][j]))));
        }
    }

    float bv[4];
    #pragma unroll
    for (int j = 0; j < 4; ++j) bv[j] = bias[h*DH_ + tx*4 + j];

    #pragma unroll
    for (int i = 0; i < 4; ++i) {
        float4 o4;
        o4.x = acc[i][0] + bv[0];
        o4.y = acc[i][1] + bv[1];
        o4.z = acc[i][2] + bv[2];
        o4.w = acc[i][3] + bv[3];
        *(float4*)(out + ((size_t)(bh*S_ + s0 + ty*4 + i))*DH_ + tx*4) = o4;
    }
}

// ---------------------------------------------------------------------------
// Kernel 2: causal flash attention (fp32), D=64.
// grid (S/64, B*H): one block per 64-row Q tile of one (b,h). Online softmax,
// 16-lane shuffle row reductions. K kept ROW-major (dot-product QK^T) with
// the same XOR swizzle -> float4 staging writes and conflict-free reads.
// Masked entries -> -inf -> __expf underflows to exactly 0.0f, matching the
// reference's -1e5 fill (exp(-1e5 - m) == 0.0f in fp32).
// ---------------------------------------------------------------------------
__global__ __launch_bounds__(256) void attn_kernel(
    const float* __restrict__ q, const float* __restrict__ kkk, const float* __restrict__ v,
    float* __restrict__ z)
{
    const int bh = blockIdx.y;
    const int qt = (int)gridDim.x - 1 - (int)blockIdx.x;   // big blocks launch first

    __shared__ float Qs[64][64];   // swizzled
    __shared__ float Ks[64][64];   // swizzled, row-major
    __shared__ float Vs[64][64];   // plain (B-operand)
    __shared__ float Ps[64][64];   // swizzled

    const int t  = threadIdx.x;
    const int tx = t & 15, ty = t >> 4;
    const int keyY = ty & 7, keyX = tx & 7;

    #pragma unroll
    for (int l = 0; l < 4; ++l) {
        const int lin = t + l*256;
        const int row = lin >> 4, c4 = lin & 15;
        const float4 f = *(const float4*)(q + ((size_t)(bh*S_ + qt*64 + row))*DH_ + c4*4);
        *(float4*)&Qs[row][(c4 ^ ((row>>2)&7)) << 2] = f;
    }

    float m[4], lsum[4];
    float o[4][4] = {};
    #pragma unroll
    for (int i = 0; i < 4; ++i) { m[i] = -INFINITY; lsum[i] = 0.f; }

    for (int kt = 0; kt <= qt; ++kt) {
        __syncthreads();
        #pragma unroll
        for (int l = 0; l < 4; ++l) {
            const int lin = t + l*256;
            const int row = lin >> 4, c4 = lin & 15;
            const float4 f = *(const float4*)(kkk + ((size_t)(bh*S_ + kt*64 + row))*DH_ + c4*4);
            *(float4*)&Ks[row][(c4 ^ ((row>>2)&7)) << 2] = f;
            const float4 g = *(const float4*)(v + ((size_t)(bh*S_ + kt*64 + row))*DH_ + c4*4);
            *(float4*)&Vs[row][c4*4] = g;
        }
        __syncthreads();

        // S = Q K^T (dot-product form; both operands row-major swizzled)
        float s[4][4] = {};
        #pragma unroll
        for (int d4 = 0; d4 < 16; ++d4) {
            float a[4][4], kf[4][4];
            #pragma unroll
            for (int i = 0; i < 4; ++i)
                *(float4*)a[i] = *(const float4*)&Qs[ty*4+i][(d4 ^ keyY) << 2];
            #pragma unroll
            for (int j = 0; j < 4; ++j)
                *(float4*)kf[j] = *(const float4*)&Ks[tx*4+j][(d4 ^ keyX) << 2];
            #pragma unroll
            for (int i = 0; i < 4; ++i)
                #pragma unroll
                for (int j = 0; j < 4; ++j)
                    s[i][j] = fmaf(a[i][0], kf[j][0],
                              fmaf(a[i][1], kf[j][1],
                              fmaf(a[i][2], kf[j][2],
                              fmaf(a[i][3], kf[j][3], s[i][j]))));
        }

        #pragma unroll
        for (int i = 0; i < 4; ++i)
            #pragma unroll
            for (int j = 0; j < 4; ++j)
                s[i][j] *= 0.125f;                     // 1/sqrt(64)

        if (kt == qt) {                                // causal mask, diagonal tile
            #pragma unroll
            for (int i = 0; i < 4; ++i)
                #pragma unroll
                for (int j = 0; j < 4; ++j)
                    if (tx*4 + j > ty*4 + i) s[i][j] = -INFINITY;
        }

        // online softmax (row stats redundant across the 16 lanes of a row group)
        #pragma unroll
        for (int i = 0; i < 4; ++i) {
            float mloc = fmaxf(fmaxf(s[i][0], s[i][1]), fmaxf(s[i][2], s[i][3]));
            #pragma unroll
            for (int off = 1; off < 16; off <<= 1)
                mloc = fmaxf(mloc, __shfl_xor(mloc, off));
            const float mnew = fmaxf(m[i], mloc);
            const float corr = __expf(m[i] - mnew);    // first iter: exp(-inf)=0, o==0
            float ps = 0.f;
            #pragma unroll
            for (int j = 0; j < 4; ++j) {
                const float p = __expf(s[i][j] - mnew);
                s[i][j] = p;
                ps += p;
            }
            #pragma unroll
            for (int off = 1; off < 16; off <<= 1)
                ps += __shfl_xor(ps, off);
            lsum[i] = lsum[i]*corr + ps;
            m[i] = mnew;
            #pragma unroll
            for (int j = 0; j < 4; ++j) o[i][j] *= corr;
            *(float4*)&Ps[ty*4+i][(tx ^ keyY) << 2] = *(float4*)s[i];
        }
        __syncthreads();

        // O += P V
        #pragma unroll
        for (int c4 = 0; c4 < 16; ++c4) {
            float p[4][4], vv[4][4];
            #pragma unroll
            for (int i = 0; i < 4; ++i)
                *(float4*)p[i] = *(const float4*)&Ps[ty*4+i][(c4 ^ keyY) << 2];
            #pragma unroll
            for (int qq = 0; qq < 4; ++qq)
                *(float4*)vv[qq] = *(const float4*)&Vs[c4*4+qq][tx*4];
            #pragma unroll
            for (int i = 0; i < 4; ++i)
                #pragma unroll
                for (int j = 0; j < 4; ++j)
                    o[i][j] = fmaf(p[i][0], vv[0][j],
                              fmaf(p[i][1], vv[1][j],
                              fmaf(p[i][2], vv[2][j],
                              fmaf(p[i][3], vv[3][j], o[i][j]))));
        }
    }

    #pragma unroll
    for (int i = 0; i < 4; ++i) {
        const float inv = 1.0f / lsum[i];
        float4 o4;
        o4.x = o[i][0]*inv; o4.y = o[i][1]*inv; o4.z = o[i][2]*inv; o4.w = o[i][3]*inv;
        *(float4*)(z + ((size_t)(bh*S_ + qt*64 + ty*4 + i))*DH_ + tx*4) = o4;
    }
}

// ---------------------------------------------------------------------------
// Kernel 3: per-head output projection.
// out[b,s,h,m] = sum_e z[b,h,s,e]*WO[h,e,m] + bO[m]/H
// grid (S/64, DM/64, B*H): 64x64 output tile, single K=64 pass.
// ---------------------------------------------------------------------------
__global__ __launch_bounds__(256) void oproj_kernel(
    const float* __restrict__ zin, const float* __restrict__ WO, const float* __restrict__ bO,
    float* __restrict__ out)
{
    const int bh = blockIdx.z;
    const int b  = bh / H_, h = bh % H_;
    const int s0 = blockIdx.x * 64;
    const int m0 = blockIdx.y * 64;

    __shared__ float Zs[64][64];   // swizzled A-tile
    __shared__ float Ws[64][64];   // plain B-tile

    const int t  = threadIdx.x;
    const int tx = t & 15, ty = t >> 4;
    const int keyY = ty & 7;

    #pragma unroll
    for (int l = 0; l < 4; ++l) {
        const int lin = t + l*256;
        const int row = lin >> 4, c4 = lin & 15;
        const float4 fz = *(const float4*)(zin + ((size_t)(bh*S_ + s0 + row))*DH_ + c4*4);
        *(float4*)&Zs[row][(c4 ^ ((row>>2)&7)) << 2] = fz;
        const float4 fw = *(const float4*)(WO + ((size_t)(h*DH_ + row))*DM_ + m0 + c4*4);
        *(float4*)&Ws[row][c4*4] = fw;
    }
    __syncthreads();

    float acc[4][4] = {};
    #pragma unroll
    for (int e4 = 0; e4 < 16; ++e4) {
        float a[4][4], w[4][4];
        #pragma unroll
        for (int i = 0; i < 4; ++i)
            *(float4*)a[i] = *(const float4*)&Zs[ty*4+i][(e4 ^ keyY) << 2];
        #pragma unroll
        for (int qq = 0; qq < 4; ++qq)
            *(float4*)w[qq] = *(const float4*)&Ws[e4*4+qq][tx*4];
        #pragma unroll
        for (int i = 0; i < 4; ++i)
            #pragma unroll
            for (int j = 0; j < 4; ++j)
                acc[i][j] = fmaf(a[i][0], w[0][j],
                            fmaf(a[i][1], w[1][j],
                            fmaf(a[i][2], w[2][j],
                            fmaf(a[i][3], w[3][j], acc[i][j]))));
    }

    float bv[4];
    #pragma unroll
    for (int j = 0; j < 4; ++j) bv[j] = bO[m0 + tx*4 + j] / (float)H_;

    #pragma unroll
    for (int i = 0; i < 4; ++i) {
        const int r = s0 + ty*4 + i;
        float4 o4;
        o4.x = acc[i][0] + bv[0];
        o4.y = acc[i][1] + bv[1];
        o4.z = acc[i][2] + bv[2];
        o4.w = acc[i][3] + bv[3];
        *(float4*)(out + ((size_t)((b*S_ + r)*H_ + h))*DM_ + m0 + tx*4) = o4;
    }
}

// ---------------------------------------------------------------------------
extern "C" void kernel_launch(void* const* d_in, const int* in_sizes, int n_in,
                              void* d_out, int out_size, void* d_ws, size_t ws_size,
                              hipStream_t stream)
{
    const float* Xq = (const float*)d_in[0];
    const float* Xk = (const float*)d_in[1];
    const float* Xv = (const float*)d_in[2];
    const float* WQ = (const float*)d_in[3];
    const float* bQ = (const float*)d_in[4];
    const float* WK = (const float*)d_in[5];
    const float* bK = (const float*)d_in[6];
    const float* WV = (const float*)d_in[7];
    const float* bV = (const float*)d_in[8];
    const float* WO = (const float*)d_in[9];
    const float* bO = (const float*)d_in[10];
    float* out = (float*)d_out;
    (void)in_sizes; (void)n_in; (void)out_size; (void)ws_size;

    // workspace: q,k,v,z each [B][H][S][DH] fp32 = 12.58 MB -> 50.3 MB total
    const size_t per = (size_t)B_ * H_ * S_ * DH_;
    float* qb = (float*)d_ws;
    float* kb = qb + per;
    float* vb = kb + per;
    float* zb = vb + per;

    dim3 gp(S_/64, B_*H_, 3);
    qkv_proj_kernel<<<gp, 256, 0, stream>>>(Xq, Xk, Xv, WQ, bQ, WK, bK, WV, bV, qb, kb, vb);

    dim3 ga(S_/64, B_*H_);
    attn_kernel<<<ga, 256, 0, stream>>>(qb, kb, vb, zb);

    dim3 go(S_/64, DM_/64, B_*H_);
    oproj_kernel<<<go, 256, 0, stream>>>(zb, WO, bO, out);
}

// Round 6
// 674.642 us; speedup vs baseline: 1.9328x; 1.9328x over previous
//
#include <hip/hip_runtime.h>
#include <math.h>
#include <stdint.h>

#define B_ 2
#define S_ 2048
#define H_ 12
#define DM_ 768
#define DH_ 64

// MFMA fragment types (guide §3: 16x16x32 bf16 -> A/B = 8 bf16 (4 VGPR), C/D = 4 f32)
typedef short bf8_t __attribute__((ext_vector_type(8)));
typedef float f4_t  __attribute__((ext_vector_type(4)));

#define MFMA16(a,b,c) __builtin_amdgcn_mfma_f32_16x16x32_bf16((a),(b),(c),0,0,0)

// fp32 -> bf16 round-to-nearest-even (inputs are finite; no NaN handling needed)
__device__ __forceinline__ unsigned short f2b(float f) {
    union { float f; uint32_t u; } v; v.f = f;
    const uint32_t r = v.u + 0x7fffu + ((v.u >> 16) & 1u);
    return (unsigned short)(r >> 16);
}
__device__ __forceinline__ uint32_t f2b2(float lo, float hi) {
    return (uint32_t)f2b(lo) | ((uint32_t)f2b(hi) << 16);
}

// ===========================================================================
// LDS layout (all kernels): bf16 tiles [R][64], row = 128B = 8 x 16B slots.
// Content chunk c of row r lives at slot (c ^ (r&7)): every b128 access is
// phase-balanced (8 lanes per bank-quad = the 1KB/instr throughput floor).
// MFMA frag read: lane l -> row base + (l&15), chunk kk*4 + (l>>4).
// Since all row bases are multiples of 8, (row&7) == (l&15)&7 == l&7 on reads.
// ===========================================================================

// ---------------------------------------------------------------------------
// Kernel 0: weights fp32 -> bf16, pre-transposed.
//   wt  [which][h][n=dh][k=dm]  (B-operand for qkv:  W[h][k][n] transposed)
//   wot [h][m=dm][e=dh]        (B-operand for oproj: WO[h][e][m] transposed)
// ---------------------------------------------------------------------------
__global__ __launch_bounds__(256) void convert_w(
    const float* __restrict__ WQ, const float* __restrict__ WK, const float* __restrict__ WV,
    const float* __restrict__ WO,
    unsigned short* __restrict__ wt, unsigned short* __restrict__ wot)
{
    const int idx = blockIdx.x * 256 + threadIdx.x;
    const int nqkv = 3 * H_ * DM_ * DH_;
    if (idx < nqkv) {
        const int which = idx / (H_*DM_*DH_);
        const int r     = idx % (H_*DM_*DH_);
        const int h  = r / (DM_*DH_);
        const int r2 = r % (DM_*DH_);
        const int k  = r2 / DH_;
        const int n  = r2 % DH_;
        const float* __restrict__ W = which==0 ? WQ : (which==1 ? WK : WV);
        wt[((size_t)(which*H_ + h)*DH_ + n)*DM_ + k] = f2b(W[r]);
    } else {
        const int j  = idx - nqkv;          // over [h][e][m]
        const int h  = j / (DH_*DM_);
        const int r2 = j % (DH_*DM_);
        const int e  = r2 / DM_;
        const int mc = r2 % DM_;
        wot[((size_t)h*DM_ + mc)*DH_ + e] = f2b(WO[j]);
    }
}

// ---------------------------------------------------------------------------
// Kernel 1: fused QKV projection (bf16 MFMA, fp32 X converted in-flight).
// grid (S/128, B*H, 3). Block: 128 s-rows x 64 cols; 4 waves, wave = 32x64
// (2 m-frags x 4 n-frags), BK=64 (2 MFMA k-steps). Outputs bf16:
//   which 0 -> q [bh][s][d], 1 -> k [bh][s][d], 2 -> V^T [bh][d][s]
// ---------------------------------------------------------------------------
__global__ __launch_bounds__(256) void qkv_proj(
    const float* __restrict__ Xq, const float* __restrict__ Xk, const float* __restrict__ Xv,
    const float* __restrict__ bQ, const float* __restrict__ bK, const float* __restrict__ bV,
    const unsigned short* __restrict__ wt,
    unsigned short* __restrict__ qb, unsigned short* __restrict__ kb,
    unsigned short* __restrict__ vtb)
{
    const int which = blockIdx.z;
    const float* __restrict__ X    = which==0 ? Xq : (which==1 ? Xk : Xv);
    const float* __restrict__ bias = which==0 ? bQ : (which==1 ? bK : bV);
    const int bh = blockIdx.y, b = bh / H_, h = bh % H_;
    const int s0 = blockIdx.x * 128;

    __shared__ __align__(16) unsigned short Xs[128][64];
    __shared__ __align__(16) unsigned short Ws[64][64];

    const int t = threadIdx.x, w = t >> 6, l = t & 63;
    const unsigned short* __restrict__ Wth = wt + (size_t)(which*H_ + h) * DH_ * DM_;

    f4_t acc[2][4];
    #pragma unroll
    for (int m = 0; m < 2; ++m)
        #pragma unroll
        for (int n = 0; n < 4; ++n)
            #pragma unroll
            for (int j = 0; j < 4; ++j) acc[m][n][j] = 0.f;

    for (int kt = 0; kt < DM_/64; ++kt) {
        const int k0 = kt*64;
        // load phase (regs) — X fp32 (2 float4 = 8 elems/unit), Wt bf16 (1 uint4)
        float4 xa[4][2];
        #pragma unroll
        for (int u = 0; u < 4; ++u) {
            const int uid = t + u*256, row = uid >> 3, sl = uid & 7;
            const float* p = X + ((size_t)((b*S_ + s0 + row)*H_ + h))*DM_ + k0 + sl*8;
            xa[u][0] = *(const float4*)p;
            xa[u][1] = *(const float4*)(p + 4);
        }
        uint4 wv[2];
        #pragma unroll
        for (int i2 = 0; i2 < 2; ++i2) {
            const int row = (w*2 + i2)*8 + (l>>3);
            wv[i2] = *(const uint4*)(Wth + (size_t)row*DM_ + k0 + (l&7)*8);
        }
        __syncthreads();                         // prev-iter LDS reads done
        // write phase (convert + swizzled b128 writes)
        #pragma unroll
        for (int u = 0; u < 4; ++u) {
            const int uid = t + u*256, row = uid >> 3, sl = uid & 7;
            uint4 pk;
            pk.x = f2b2(xa[u][0].x, xa[u][0].y);
            pk.y = f2b2(xa[u][0].z, xa[u][0].w);
            pk.z = f2b2(xa[u][1].x, xa[u][1].y);
            pk.w = f2b2(xa[u][1].z, xa[u][1].w);
            *(uint4*)&Xs[row][(sl ^ (row&7))*8] = pk;
        }
        #pragma unroll
        for (int i2 = 0; i2 < 2; ++i2) {
            const int row = (w*2 + i2)*8 + (l>>3);
            *(uint4*)&Ws[row][((l&7) ^ (l>>3))*8] = wv[i2];
        }
        __syncthreads();                         // tile visible
        // MFMA
        #pragma unroll
        for (int kk = 0; kk < 2; ++kk) {
            const int sl = kk*4 + (l>>4);
            bf8_t a[2], bb[4];
            #pragma unroll
            for (int m = 0; m < 2; ++m)
                a[m] = *(const bf8_t*)&Xs[w*32 + m*16 + (l&15)][(sl ^ (l&7))*8];
            #pragma unroll
            for (int n = 0; n < 4; ++n)
                bb[n] = *(const bf8_t*)&Ws[n*16 + (l&15)][(sl ^ (l&7))*8];
            #pragma unroll
            for (int m = 0; m < 2; ++m)
                #pragma unroll
                for (int n = 0; n < 4; ++n)
                    acc[m][n] = MFMA16(a[m], bb[n], acc[m][n]);
        }
    }

    float bv[4];
    #pragma unroll
    for (int n = 0; n < 4; ++n) bv[n] = bias[h*DH_ + n*16 + (l&15)];

    // C/D layout (m89-verified): col = l&15 (+16n), row = 4*(l>>4)+r (+16m+32w)
    if (which < 2) {
        unsigned short* __restrict__ O = (which==0 ? qb : kb) + (size_t)bh * S_ * DH_;
        #pragma unroll
        for (int m = 0; m < 2; ++m)
            #pragma unroll
            for (int n = 0; n < 4; ++n)
                #pragma unroll
                for (int r = 0; r < 4; ++r) {
                    const int s = s0 + w*32 + m*16 + 4*(l>>4) + r;
                    O[(size_t)s*DH_ + n*16 + (l&15)] = f2b(acc[m][n][r] + bv[n]);
                }
    } else {
        unsigned short* __restrict__ VT = vtb + (size_t)bh * DH_ * S_;
        #pragma unroll
        for (int m = 0; m < 2; ++m)
            #pragma unroll
            for (int n = 0; n < 4; ++n)
                #pragma unroll
                for (int r = 0; r < 4; ++r) {
                    const int s = s0 + w*32 + m*16 + 4*(l>>4) + r;
                    VT[(size_t)(n*16 + (l&15))*S_ + s] = f2b(acc[m][n][r] + bv[n]);
                }
    }
}

// ---------------------------------------------------------------------------
// Kernel 2: causal flash attention, bf16 MFMA, fp32 online softmax.
// grid (S/64, B*H). Block: 64 q-rows, 4 waves (wave = 16 q-rows x 64 k-cols).
// K/V tiles double-buffered; staging split load-early/write-late (T14).
// Q staged through Ps once, then Ps holds per-wave P (wave-private region).
// Masked -> -inf -> __expf underflows to exactly 0 (matches -1e5 fill).
// ---------------------------------------------------------------------------
__global__ __launch_bounds__(256) void attn(
    const unsigned short* __restrict__ qb, const unsigned short* __restrict__ kb,
    const unsigned short* __restrict__ vtb, unsigned short* __restrict__ zb)
{
    const int bh = blockIdx.y;
    const int qt = (int)gridDim.x - 1 - (int)blockIdx.x;   // big tiles launch first

    __shared__ __align__(16) unsigned short Ks[2][64][64];
    __shared__ __align__(16) unsigned short Vs[2][64][64]; // [d][s_k] (from V^T)
    __shared__ __align__(16) unsigned short Ps[64][64];    // Q at start, then P

    const int t = threadIdx.x, w = t >> 6, l = t & 63;
    const unsigned short* __restrict__ Q  = qb  + ((size_t)bh*S_ + qt*64)*DH_;
    const unsigned short* __restrict__ K  = kb  + (size_t)bh*S_*DH_;
    const unsigned short* __restrict__ VT = vtb + (size_t)bh*DH_*S_;

    {   // prologue: stage Q + K/V tile 0
        uint4 qv[2], kv[2], vv[2];
        #pragma unroll
        for (int i2 = 0; i2 < 2; ++i2) {
            const int row = (w*2 + i2)*8 + (l>>3);
            qv[i2] = *(const uint4*)(Q  + (size_t)row*DH_ + (l&7)*8);
            kv[i2] = *(const uint4*)(K  + (size_t)row*DH_ + (l&7)*8);
            vv[i2] = *(const uint4*)(VT + (size_t)row*S_  + (l&7)*8);
        }
        #pragma unroll
        for (int i2 = 0; i2 < 2; ++i2) {
            const int row = (w*2 + i2)*8 + (l>>3);
            const int sl = ((l&7) ^ (l>>3))*8;
            *(uint4*)&Ps[row][sl]    = qv[i2];
            *(uint4*)&Ks[0][row][sl] = kv[i2];
            *(uint4*)&Vs[0][row][sl] = vv[i2];
        }
    }
    __syncthreads();

    bf8_t qf[2];
    #pragma unroll
    for (int kk = 0; kk < 2; ++kk)
        qf[kk] = *(const bf8_t*)&Ps[w*16 + (l&15)][((kk*4 + (l>>4)) ^ (l&7))*8];

    float m_[4], l_[4];
    f4_t o_[4];
    #pragma unroll
    for (int j = 0; j < 4; ++j) { m_[j] = -INFINITY; l_[j] = 0.f; }
    #pragma unroll
    for (int n = 0; n < 4; ++n)
        #pragma unroll
        for (int j = 0; j < 4; ++j) o_[n][j] = 0.f;

    int buf = 0;
    for (int kt = 0; kt <= qt; ++kt) {
        const bool pfetch = (kt < qt);
        uint4 kv[2], vv[2];
        if (pfetch) {                            // issue next-tile loads early
            #pragma unroll
            for (int i2 = 0; i2 < 2; ++i2) {
                const int row = (w*2 + i2)*8 + (l>>3);
                kv[i2] = *(const uint4*)(K  + ((size_t)(kt+1)*64 + row)*DH_ + (l&7)*8);
                vv[i2] = *(const uint4*)(VT + (size_t)row*S_ + (kt+1)*64 + (l&7)*8);
            }
        }
        // S = Q K^T
        f4_t s_[4];
        #pragma unroll
        for (int n = 0; n < 4; ++n)
            #pragma unroll
            for (int j = 0; j < 4; ++j) s_[n][j] = 0.f;
        #pragma unroll
        for (int kk = 0; kk < 2; ++kk) {
            const int sl = kk*4 + (l>>4);
            #pragma unroll
            for (int n = 0; n < 4; ++n) {
                const bf8_t kf = *(const bf8_t*)&Ks[buf][n*16 + (l&15)][(sl ^ (l&7))*8];
                s_[n] = MFMA16(qf[kk], kf, s_[n]);
            }
        }
        #pragma unroll
        for (int n = 0; n < 4; ++n)
            #pragma unroll
            for (int j = 0; j < 4; ++j) s_[n][j] *= 0.125f;       // 1/sqrt(64)
        if (kt == qt) {                                           // causal diag
            #pragma unroll
            for (int n = 0; n < 4; ++n)
                #pragma unroll
                for (int j = 0; j < 4; ++j)
                    if (n*16 + (l&15) > w*16 + 4*(l>>4) + j) s_[n][j] = -INFINITY;
        }
        // online softmax (rows live in 16-lane groups; 4 rows per lane = regs)
        float corr[4];
        #pragma unroll
        for (int j = 0; j < 4; ++j) {
            float mx = fmaxf(fmaxf(s_[0][j], s_[1][j]), fmaxf(s_[2][j], s_[3][j]));
            #pragma unroll
            for (int off = 1; off < 16; off <<= 1)
                mx = fmaxf(mx, __shfl_xor(mx, off));
            const float mn = fmaxf(m_[j], mx);
            corr[j] = __expf(m_[j] - mn);
            float ps = 0.f;
            #pragma unroll
            for (int n = 0; n < 4; ++n) {
                const float p = __expf(s_[n][j] - mn);
                s_[n][j] = p;
                ps += p;
            }
            #pragma unroll
            for (int off = 1; off < 16; off <<= 1)
                ps += __shfl_xor(ps, off);
            l_[j] = l_[j]*corr[j] + ps;
            m_[j] = mn;
        }
        // write P (C-layout -> [q][s_k] bf16, swizzled), rescale O
        #pragma unroll
        for (int n = 0; n < 4; ++n)
            #pragma unroll
            for (int j = 0; j < 4; ++j) {
                const int row = w*16 + 4*(l>>4) + j;
                const int col = n*16 + (l&15);
                Ps[row][((col>>3) ^ (row&7))*8 + (col&7)] = f2b(s_[n][j]);
                o_[n][j] *= corr[j];
            }
        __syncthreads();   // cross-lane P visibility (conservative; uniform)
        // O += P V
        #pragma unroll
        for (int kk = 0; kk < 2; ++kk) {
            const int sl = kk*4 + (l>>4);
            const bf8_t pfr = *(const bf8_t*)&Ps[w*16 + (l&15)][(sl ^ (l&7))*8];
            #pragma unroll
            for (int n = 0; n < 4; ++n) {
                const bf8_t vf = *(const bf8_t*)&Vs[buf][n*16 + (l&15)][(sl ^ (l&7))*8];
                o_[n] = MFMA16(pfr, vf, o_[n]);
            }
        }
        // write prefetched tile late (T14)
        if (pfetch) {
            #pragma unroll
            for (int i2 = 0; i2 < 2; ++i2) {
                const int row = (w*2 + i2)*8 + (l>>3);
                const int sl = ((l&7) ^ (l>>3))*8;
                *(uint4*)&Ks[buf^1][row][sl] = kv[i2];
                *(uint4*)&Vs[buf^1][row][sl] = vv[i2];
            }
        }
        __syncthreads();
        buf ^= 1;
    }
    // epilogue: normalize, store z bf16 [bh][s][d]
    unsigned short* __restrict__ Z = zb + ((size_t)bh*S_ + qt*64)*DH_;
    #pragma unroll
    for (int j = 0; j < 4; ++j) {
        const float inv = 1.0f / l_[j];
        #pragma unroll
        for (int n = 0; n < 4; ++n) {
            const int row = w*16 + 4*(l>>4) + j;
            Z[(size_t)row*DH_ + n*16 + (l&15)] = f2b(o_[n][j] * inv);
        }
    }
}

// ---------------------------------------------------------------------------
// Kernel 3: per-head output projection, bf16 MFMA, fp32 out.
// out[b,s,h,m] = sum_e z[bh,s,e]*WO[h,e,m] + bO[m]/H
// grid (S/128, DM/128, B*H). Block 128x128; 4 waves = 2x2 of 64x64; K=64.
// ---------------------------------------------------------------------------
__global__ __launch_bounds__(256) void oproj(
    const unsigned short* __restrict__ zb, const unsigned short* __restrict__ wot,
    const float* __restrict__ bO, float* __restrict__ out)
{
    const int bh = blockIdx.z, b = bh / H_, h = bh % H_;
    const int s0 = blockIdx.x * 128;
    const int m0 = blockIdx.y * 128;

    __shared__ __align__(16) unsigned short Zs[128][64];
    __shared__ __align__(16) unsigned short Ms[128][64];   // [m][e]

    const int t = threadIdx.x, w = t >> 6, l = t & 63;
    const unsigned short* __restrict__ Zg = zb  + (size_t)bh*S_*DH_;
    const unsigned short* __restrict__ Wg = wot + (size_t)h*DM_*DH_;

    #pragma unroll
    for (int i2 = 0; i2 < 4; ++i2) {
        const int row = (w*4 + i2)*8 + (l>>3);
        const int sl = ((l&7) ^ (l>>3))*8;
        *(uint4*)&Zs[row][sl] = *(const uint4*)(Zg + (size_t)(s0 + row)*DH_ + (l&7)*8);
        *(uint4*)&Ms[row][sl] = *(const uint4*)(Wg + (size_t)(m0 + row)*DH_ + (l&7)*8);
    }
    __syncthreads();

    const int wr = w >> 1, wc = w & 1;
    f4_t acc[4][4];
    #pragma unroll
    for (int mf = 0; mf < 4; ++mf)
        #pragma unroll
        for (int n = 0; n < 4; ++n)
            #pragma unroll
            for (int j = 0; j < 4; ++j) acc[mf][n][j] = 0.f;

    #pragma unroll
    for (int kk = 0; kk < 2; ++kk) {
        const int sl = kk*4 + (l>>4);
        bf8_t a[4], bb[4];
        #pragma unroll
        for (int mf = 0; mf < 4; ++mf)
            a[mf] = *(const bf8_t*)&Zs[wr*64 + mf*16 + (l&15)][(sl ^ (l&7))*8];
        #pragma unroll
        for (int n = 0; n < 4; ++n)
            bb[n] = *(const bf8_t*)&Ms[wc*64 + n*16 + (l&15)][(sl ^ (l&7))*8];
        #pragma unroll
        for (int mf = 0; mf < 4; ++mf)
            #pragma unroll
            for (int n = 0; n < 4; ++n)
                acc[mf][n] = MFMA16(a[mf], bb[n], acc[mf][n]);
    }

    float bo[4];
    #pragma unroll
    for (int n = 0; n < 4; ++n)
        bo[n] = bO[m0 + wc*64 + n*16 + (l&15)] * (1.0f / H_);

    #pragma unroll
    for (int mf = 0; mf < 4; ++mf)
        #pragma unroll
        for (int n = 0; n < 4; ++n)
            #pragma unroll
            for (int r = 0; r < 4; ++r) {
                const int s    = s0 + wr*64 + mf*16 + 4*(l>>4) + r;
                const int mcol = m0 + wc*64 + n*16 + (l&15);
                out[((size_t)(b*S_ + s)*H_ + h)*DM_ + mcol] = acc[mf][n][r] + bo[n];
            }
}

// ---------------------------------------------------------------------------
extern "C" void kernel_launch(void* const* d_in, const int* in_sizes, int n_in,
                              void* d_out, int out_size, void* d_ws, size_t ws_size,
                              hipStream_t stream)
{
    const float* Xq = (const float*)d_in[0];
    const float* Xk = (const float*)d_in[1];
    const float* Xv = (const float*)d_in[2];
    const float* WQ = (const float*)d_in[3];
    const float* bQ = (const float*)d_in[4];
    const float* WK = (const float*)d_in[5];
    const float* bK = (const float*)d_in[6];
    const float* WV = (const float*)d_in[7];
    const float* bV = (const float*)d_in[8];
    const float* WO = (const float*)d_in[9];
    const float* bO = (const float*)d_in[10];
    float* out = (float*)d_out;
    (void)in_sizes; (void)n_in; (void)out_size; (void)ws_size;

    // ws (bf16): q, k, V^T, z each [bh][...] 6.29MB; wt 3.4MB; wot 1.1MB  (~30MB)
    const size_t per = (size_t)B_ * H_ * S_ * DH_;
    unsigned short* qbuf  = (unsigned short*)d_ws;
    unsigned short* kbuf  = qbuf  + per;
    unsigned short* vtbuf = kbuf  + per;
    unsigned short* zbuf  = vtbuf + per;
    unsigned short* wt    = zbuf  + per;
    unsigned short* wot   = wt + (size_t)3*H_*DH_*DM_;

    convert_w<<<dim3((3*H_*DM_*DH_ + H_*DH_*DM_)/256), 256, 0, stream>>>(WQ, WK, WV, WO, wt, wot);

    qkv_proj<<<dim3(S_/128, B_*H_, 3), 256, 0, stream>>>(
        Xq, Xk, Xv, bQ, bK, bV, wt, qbuf, kbuf, vtbuf);

    attn<<<dim3(S_/64, B_*H_), 256, 0, stream>>>(qbuf, kbuf, vtbuf, zbuf);

    oproj<<<dim3(S_/128, DM_/128, B_*H_), 256, 0, stream>>>(zbuf, wot, bO, out);
}